// Round 1
// baseline (13905.760 us; speedup 1.0000x reference)
//
#include <hip/hip_runtime.h>
#include <math.h>

constexpr int SEQ   = 256;
constexpr int BATCH = 512;
constexpr int INDIM = 300;
constexpr int HDIM  = 512;
constexpr int LDIM  = 256;
constexpr int G4    = 4 * HDIM;   // 2048

// ---------------------------------------------------------------------------
// Per-timestep gates GEMM:
//   gates[b][g] = sum_i x_t[b][i]*W_ih[g][i] + sum_j h[b][j]*W_hh[g][j]
//                 + b_ih[g] + b_hh[g]
// M=512 (batch), N=2048 (gates), K=300 then 512. Both operands K-contiguous.
// 64x64 tile per block, 256 threads, 4x4 micro-tile per thread.
// ---------------------------------------------------------------------------
__global__ __launch_bounds__(256) void gates_gemm_kernel(
    const float* __restrict__ xt,    // [BATCH][INDIM]
    const float* __restrict__ Wih,   // [G4][INDIM]
    const float* __restrict__ hprev, // [BATCH][HDIM]
    const float* __restrict__ Whh,   // [G4][HDIM]
    const float* __restrict__ bih,   // [G4]
    const float* __restrict__ bhh,   // [G4]
    float* __restrict__ gates)       // [BATCH][G4]
{
    __shared__ float As[16][64];
    __shared__ float Bs[16][64];

    const int tid  = threadIdx.x;
    const int ty   = tid >> 4;        // 0..15 -> output rows ty*4..ty*4+3
    const int tx   = tid & 15;        // 0..15 -> output cols tx*4..tx*4+3
    const int rowA = blockIdx.x * 64; // batch tile origin
    const int colB = blockIdx.y * 64; // gate tile origin

    const int ldr = tid >> 2;         // 0..63 tile row loaded by this thread
    const int ldk = (tid & 3) << 2;   // 0,4,8,12 k offset loaded

    float acc[4][4] = {};

    for (int phase = 0; phase < 2; ++phase) {
        const float* A  = phase ? hprev : xt;
        const float* Bw = phase ? Whh   : Wih;
        const int K     = phase ? HDIM  : INDIM;
        const int lda   = K;  // row stride == K for all four matrices

        for (int k0 = 0; k0 < K; k0 += 16) {
            const int gk = k0 + ldk;
            const float* pa = A  + (size_t)(rowA + ldr) * lda + gk;
            const float* pb = Bw + (size_t)(colB + ldr) * lda + gk;
            float4 av, bv;
            if (gk + 3 < K) {
                av = *(const float4*)pa;
                bv = *(const float4*)pb;
            } else {  // K=300 tail tile: zero-pad
                av.x = (gk + 0 < K) ? pa[0] : 0.f;
                av.y = (gk + 1 < K) ? pa[1] : 0.f;
                av.z = (gk + 2 < K) ? pa[2] : 0.f;
                av.w = (gk + 3 < K) ? pa[3] : 0.f;
                bv.x = (gk + 0 < K) ? pb[0] : 0.f;
                bv.y = (gk + 1 < K) ? pb[1] : 0.f;
                bv.z = (gk + 2 < K) ? pb[2] : 0.f;
                bv.w = (gk + 3 < K) ? pb[3] : 0.f;
            }
            __syncthreads();  // previous iteration's LDS reads complete
            As[ldk + 0][ldr] = av.x; As[ldk + 1][ldr] = av.y;
            As[ldk + 2][ldr] = av.z; As[ldk + 3][ldr] = av.w;
            Bs[ldk + 0][ldr] = bv.x; Bs[ldk + 1][ldr] = bv.y;
            Bs[ldk + 2][ldr] = bv.z; Bs[ldk + 3][ldr] = bv.w;
            __syncthreads();
            #pragma unroll
            for (int kk = 0; kk < 16; ++kk) {
                const float4 a = *(const float4*)&As[kk][ty << 2];
                const float4 b = *(const float4*)&Bs[kk][tx << 2];
                acc[0][0] += a.x * b.x; acc[0][1] += a.x * b.y;
                acc[0][2] += a.x * b.z; acc[0][3] += a.x * b.w;
                acc[1][0] += a.y * b.x; acc[1][1] += a.y * b.y;
                acc[1][2] += a.y * b.z; acc[1][3] += a.y * b.w;
                acc[2][0] += a.z * b.x; acc[2][1] += a.z * b.y;
                acc[2][2] += a.z * b.z; acc[2][3] += a.z * b.w;
                acc[3][0] += a.w * b.x; acc[3][1] += a.w * b.y;
                acc[3][2] += a.w * b.z; acc[3][3] += a.w * b.w;
            }
        }
    }

    #pragma unroll
    for (int i = 0; i < 4; ++i) {
        const int gb = rowA + (ty << 2) + i;
        float* orow = gates + (size_t)gb * G4;
        #pragma unroll
        for (int j = 0; j < 4; ++j) {
            const int gg = colB + (tx << 2) + j;
            orow[gg] = acc[i][j] + bih[gg] + bhh[gg];
        }
    }
}

// ---------------------------------------------------------------------------
// LSTM cell elementwise update: i,f,g,o -> c,h
// ---------------------------------------------------------------------------
__global__ __launch_bounds__(256) void lstm_update_kernel(
    const float* __restrict__ gates,  // [BATCH][G4]
    float* __restrict__ c,            // [BATCH][HDIM]
    float* __restrict__ h)            // [BATCH][HDIM]
{
    const int idx = blockIdx.x * 256 + threadIdx.x;  // < BATCH*HDIM
    const int b = idx >> 9;
    const int j = idx & (HDIM - 1);
    const float* g = gates + (size_t)b * G4;
    const float ig = 1.f / (1.f + expf(-g[j]));
    const float fg = 1.f / (1.f + expf(-g[j + 512]));
    const float gg = tanhf(g[j + 1024]);
    const float og = 1.f / (1.f + expf(-g[j + 1536]));
    const float cc = fg * c[idx] + ig * gg;
    c[idx] = cc;
    h[idx] = og * tanhf(cc);
}

// ---------------------------------------------------------------------------
// BatchNorm (training stats over batch axis) folded to scale/shift:
//   y = x*s + t, s = gamma*rstd, t = beta - mean*s
// ---------------------------------------------------------------------------
__global__ __launch_bounds__(256) void bn_stats_kernel(
    const float* __restrict__ X,      // [BATCH][nfeat]
    int nfeat,
    const float* __restrict__ gamma,
    const float* __restrict__ beta,
    float* __restrict__ s,
    float* __restrict__ t)
{
    const int f = blockIdx.x * 256 + threadIdx.x;
    if (f >= nfeat) return;
    float sum = 0.f, sq = 0.f;
    for (int b = 0; b < BATCH; ++b) {
        const float v = X[(size_t)b * nfeat + f];
        sum += v; sq += v * v;
    }
    const float mean = sum * (1.f / BATCH);
    const float var  = sq * (1.f / BATCH) - mean * mean;  // biased
    const float rstd = rsqrtf(var + 1e-5f);
    const float sc   = gamma[f] * rstd;
    s[f] = sc;
    t[f] = beta[f] - mean * sc;
}

// out1[b][l] = sum_k (h[b][k]*s1[k]+t1[k]) * W1[l][k] + b1[l]
__global__ __launch_bounds__(256) void fc1_kernel(
    const float* __restrict__ h,   // [BATCH][HDIM]
    const float* __restrict__ s1,
    const float* __restrict__ t1,
    const float* __restrict__ W1,  // [LDIM][HDIM]
    const float* __restrict__ b1,  // [LDIM]
    float* __restrict__ out1)      // [BATCH][LDIM]
{
    const int b = blockIdx.x;
    const int l = threadIdx.x;  // 0..255
    const float* hb = h  + (size_t)b * HDIM;
    const float* wl = W1 + (size_t)l * HDIM;
    float acc = 0.f;
    for (int k = 0; k < HDIM; ++k)
        acc += (hb[k] * s1[k] + t1[k]) * wl[k];
    out1[(size_t)b * LDIM + l] = acc + b1[l];
}

// out[b] = 4*sigmoid( sum_l relu(out1[b][l]*s2[l]+t2[l]) * W2[l] + b2 )
__global__ __launch_bounds__(256) void final_kernel(
    const float* __restrict__ out1,  // [BATCH][LDIM]
    const float* __restrict__ s2,
    const float* __restrict__ t2,
    const float* __restrict__ W2,    // [LDIM]
    const float* __restrict__ b2,    // [1]
    float* __restrict__ out)         // [BATCH]
{
    const int b = blockIdx.x;
    const int l = threadIdx.x;
    float v = out1[(size_t)b * LDIM + l];
    v = v * s2[l] + t2[l];
    v = fmaxf(v, 0.f);
    v *= W2[l];
    #pragma unroll
    for (int off = 32; off > 0; off >>= 1) v += __shfl_down(v, off);
    __shared__ float red[4];
    if ((threadIdx.x & 63) == 0) red[threadIdx.x >> 6] = v;
    __syncthreads();
    if (threadIdx.x == 0) {
        const float ssum = red[0] + red[1] + red[2] + red[3] + b2[0];
        out[b] = 4.f / (1.f + expf(-ssum));
    }
}

// ---------------------------------------------------------------------------
extern "C" void kernel_launch(void* const* d_in, const int* in_sizes, int n_in,
                              void* d_out, int out_size, void* d_ws, size_t ws_size,
                              hipStream_t stream) {
    const float* x   = (const float*)d_in[0];   // [SEQ][BATCH][INDIM]
    const float* Wih = (const float*)d_in[1];   // [G4][INDIM]
    const float* Whh = (const float*)d_in[2];   // [G4][HDIM]
    const float* bih = (const float*)d_in[3];   // [G4]
    const float* bhh = (const float*)d_in[4];   // [G4]
    const float* g1  = (const float*)d_in[5];   // [HDIM]
    const float* be1 = (const float*)d_in[6];   // [HDIM]
    const float* W1  = (const float*)d_in[7];   // [LDIM][HDIM]
    const float* b1  = (const float*)d_in[8];   // [LDIM]
    const float* g2  = (const float*)d_in[9];   // [LDIM]
    const float* be2 = (const float*)d_in[10];  // [LDIM]
    const float* W2  = (const float*)d_in[11];  // [LDIM]
    const float* b2  = (const float*)d_in[12];  // [1]
    float* out = (float*)d_out;

    // Workspace layout (floats). Total ~1.71M floats = 6.6 MB.
    float* ws    = (float*)d_ws;
    float* h     = ws;                       // BATCH*HDIM
    float* c     = h  + BATCH * HDIM;        // BATCH*HDIM
    float* gates = c  + BATCH * HDIM;        // BATCH*G4
    float* s1    = gates + (size_t)BATCH * G4;
    float* t1    = s1 + HDIM;
    float* out1  = t1 + HDIM;                // BATCH*LDIM
    float* s2    = out1 + (size_t)BATCH * LDIM;
    float* t2    = s2 + LDIM;

    // h = c = 0 every call (deterministic; ws is poisoned once by harness)
    hipMemsetAsync(h, 0, (size_t)2 * BATCH * HDIM * sizeof(float), stream);

    const dim3 ggrid(BATCH / 64, G4 / 64);
    for (int t = 0; t < SEQ; ++t) {
        gates_gemm_kernel<<<ggrid, 256, 0, stream>>>(
            x + (size_t)t * BATCH * INDIM, Wih, h, Whh, bih, bhh, gates);
        lstm_update_kernel<<<(BATCH * HDIM) / 256, 256, 0, stream>>>(gates, c, h);
    }

    bn_stats_kernel<<<2, 256, 0, stream>>>(h, HDIM, g1, be1, s1, t1);
    fc1_kernel<<<BATCH, 256, 0, stream>>>(h, s1, t1, W1, b1, out1);
    bn_stats_kernel<<<1, 256, 0, stream>>>(out1, LDIM, g2, be2, s2, t2);
    final_kernel<<<BATCH, 256, 0, stream>>>(out1, s2, t2, W2, b2, out);
}

// Round 2
// 3571.785 us; speedup vs baseline: 3.8932x; 3.8932x over previous
//
#include <hip/hip_runtime.h>
#include <math.h>

constexpr int SEQ   = 256;
constexpr int BATCH = 512;
constexpr int INDIM = 300;
constexpr int KIH   = 320;        // INDIM zero-padded to 5*64
constexpr int HDIM  = 512;
constexpr int LDIM  = 256;
constexpr int G4    = 4 * HDIM;   // 2048

typedef _Float16 f16x8 __attribute__((ext_vector_type(8)));
typedef float    f32x4 __attribute__((ext_vector_type(4)));

// ---------------------------------------------------------------------------
// One-time per call: convert weights to fp16 (Wih zero-padded 300->320),
// pre-sum biases.
// ---------------------------------------------------------------------------
__global__ __launch_bounds__(256) void prep_kernel(
    const float* __restrict__ Wih, const float* __restrict__ Whh,
    const float* __restrict__ bih, const float* __restrict__ bhh,
    _Float16* __restrict__ Wihc,   // [G4][KIH]
    _Float16* __restrict__ Whhc,   // [G4][HDIM]
    float* __restrict__ bsum)      // [G4]
{
    const int g = blockIdx.x;      // 0..2047
    for (int col = threadIdx.x; col < KIH; col += 256)
        Wihc[(size_t)g * KIH + col] =
            (col < INDIM) ? (_Float16)Wih[(size_t)g * INDIM + col] : (_Float16)0.f;
    for (int col = threadIdx.x; col < HDIM; col += 256)
        Whhc[(size_t)g * HDIM + col] = (_Float16)Whh[(size_t)g * HDIM + col];
    if (threadIdx.x == 0) bsum[g] = bih[g] + bhh[g];
}

// ---------------------------------------------------------------------------
// Fused per-timestep kernel: gates GEMM (fp16 MFMA, fp32 accum) + LSTM cell.
// Block = 32 batch rows x 32 h-cols (=> 32x128 gate outputs, 4 gate groups).
// 256 threads = 4 waves; wave w computes gate group w (32x32 tile).
// Grid = (BATCH/32, HDIM/32) = (16,16) = 256 blocks.
// ---------------------------------------------------------------------------
__global__ __launch_bounds__(256) void fused_step_kernel(
    const float* __restrict__ xt,      // [BATCH][INDIM] fp32
    const _Float16* __restrict__ Wihc, // [G4][KIH]
    const _Float16* __restrict__ Whhc, // [G4][HDIM]
    const float* __restrict__ bsum,    // [G4]
    float* __restrict__ c,             // [BATCH][HDIM]
    float* __restrict__ h)             // [BATCH][HDIM]
{
    __shared__ _Float16 As[32][72];     // 32 x 64 (+8 pad) fp16
    __shared__ _Float16 Bs[128][72];    // 128 x 64 (+8 pad) fp16
    __shared__ float    Gb[4][32][36];  // gate preactivations

    const int tid = threadIdx.x;
    const int b0  = blockIdx.x * 32;   // batch tile origin
    const int hc0 = blockIdx.y * 32;   // h-col tile origin
    const int wid  = tid >> 6;         // wave id == gate group
    const int lane = tid & 63;

    f32x4 acc[2][2] = {};

    // Staging index precompute
    const int arow = tid >> 3;          // 0..31  A row
    const int ac8  = (tid & 7) * 8;     // 0..56  A col (8 halves)
    const int brr  = tid >> 1;          // 0..127 B row
    const int bseg = (tid & 1) * 32;    // 0/32   B col segment (32 halves)

    for (int phase = 0; phase < 2; ++phase) {
        const float* Asrc = phase ? h : xt;
        const _Float16* Bsrc = phase ? Whhc : Wihc;
        const int Kpad = phase ? HDIM : KIH;     // LDS/W padded K
        const int Kval = phase ? HDIM : INDIM;   // valid K in A source
        const int astr = phase ? HDIM : INDIM;   // A row stride (fp32)

        for (int k0 = 0; k0 < Kpad; k0 += 64) {
            // ---- stage A: fp32 -> fp16, zero-pad k >= Kval ----
            const int gk = k0 + ac8;
            const float* pa = Asrc + (size_t)(b0 + arow) * astr + gk;
            float4 u = {0.f,0.f,0.f,0.f}, v = {0.f,0.f,0.f,0.f};
            if (gk + 3 < Kval)  u = *(const float4*)pa;
            if (gk + 7 < Kval)  v = *(const float4*)(pa + 4);
            f16x8 a8;
            a8[0]=(_Float16)u.x; a8[1]=(_Float16)u.y; a8[2]=(_Float16)u.z; a8[3]=(_Float16)u.w;
            a8[4]=(_Float16)v.x; a8[5]=(_Float16)v.y; a8[6]=(_Float16)v.z; a8[7]=(_Float16)v.w;

            // ---- stage B: fp16 weights, rows = 4 gate groups x 32 cols ----
            const int grow = (brr >> 5) * HDIM + hc0 + (brr & 31);  // global W row
            const _Float16* pb = Bsrc + (size_t)grow * Kpad + k0 + bseg;
            f16x8 w0 = *(const f16x8*)(pb + 0);
            f16x8 w1 = *(const f16x8*)(pb + 8);
            f16x8 w2 = *(const f16x8*)(pb + 16);
            f16x8 w3 = *(const f16x8*)(pb + 24);

            __syncthreads();   // previous iteration's LDS reads done
            *(f16x8*)&As[arow][ac8] = a8;
            *(f16x8*)&Bs[brr][bseg + 0]  = w0;
            *(f16x8*)&Bs[brr][bseg + 8]  = w1;
            *(f16x8*)&Bs[brr][bseg + 16] = w2;
            *(f16x8*)&Bs[brr][bseg + 24] = w3;
            __syncthreads();

            // ---- MFMA: wave computes its 32x32 gate tile over BK=64 ----
            const int lr = lane & 15;        // row/col within fragment
            const int lk = (lane >> 4) * 8;  // k offset within 32
            #pragma unroll
            for (int kf = 0; kf < 2; ++kf) {
                const int kl = kf * 32 + lk;
                f16x8 a0 = *(const f16x8*)&As[lr][kl];
                f16x8 a1 = *(const f16x8*)&As[16 + lr][kl];
                f16x8 bb0 = *(const f16x8*)&Bs[wid * 32 + lr][kl];
                f16x8 bb1 = *(const f16x8*)&Bs[wid * 32 + 16 + lr][kl];
                acc[0][0] = __builtin_amdgcn_mfma_f32_16x16x32_f16(a0, bb0, acc[0][0], 0, 0, 0);
                acc[0][1] = __builtin_amdgcn_mfma_f32_16x16x32_f16(a0, bb1, acc[0][1], 0, 0, 0);
                acc[1][0] = __builtin_amdgcn_mfma_f32_16x16x32_f16(a1, bb0, acc[1][0], 0, 0, 0);
                acc[1][1] = __builtin_amdgcn_mfma_f32_16x16x32_f16(a1, bb1, acc[1][1], 0, 0, 0);
            }
        }
    }

    // ---- write gate preactivations to LDS ----
    __syncthreads();   // last MFMA consumed As/Bs; Gb region distinct but sync reads
    {
        const int cn = lane & 15;            // col within 16
        const int rb = (lane >> 4) * 4;      // row base within 16
        #pragma unroll
        for (int mi = 0; mi < 2; ++mi)
            #pragma unroll
            for (int ni = 0; ni < 2; ++ni)
                #pragma unroll
                for (int r = 0; r < 4; ++r)
                    Gb[wid][mi * 16 + rb + r][ni * 16 + cn] = acc[mi][ni][r];
    }
    __syncthreads();

    // ---- LSTM cell update: 1024 cells, 4 per thread ----
    {
        const int bl  = tid >> 3;          // 0..31 local batch
        const int jl0 = (tid & 7) * 4;     // 0..28 local h col
        const int gb  = b0 + bl;
        const int gj  = hc0 + jl0;
        const f32x4 ig = *(const f32x4*)&Gb[0][bl][jl0];
        const f32x4 fg = *(const f32x4*)&Gb[1][bl][jl0];
        const f32x4 gg = *(const f32x4*)&Gb[2][bl][jl0];
        const f32x4 og = *(const f32x4*)&Gb[3][bl][jl0];
        const f32x4 bi = *(const f32x4*)&bsum[0 * HDIM + gj];
        const f32x4 bf = *(const f32x4*)&bsum[1 * HDIM + gj];
        const f32x4 bg = *(const f32x4*)&bsum[2 * HDIM + gj];
        const f32x4 bo = *(const f32x4*)&bsum[3 * HDIM + gj];
        float* cp = c + (size_t)gb * HDIM + gj;
        float* hp = h + (size_t)gb * HDIM + gj;
        f32x4 cv = *(const f32x4*)cp;
        f32x4 hv;
        #pragma unroll
        for (int q = 0; q < 4; ++q) {
            const float iv = 1.f / (1.f + __expf(-(ig[q] + bi[q])));
            const float fv = 1.f / (1.f + __expf(-(fg[q] + bf[q])));
            const float gv = tanhf(gg[q] + bg[q]);
            const float ov = 1.f / (1.f + __expf(-(og[q] + bo[q])));
            const float cc = fv * cv[q] + iv * gv;
            cv[q] = cc;
            hv[q] = ov * tanhf(cc);
        }
        *(f32x4*)cp = cv;
        *(f32x4*)hp = hv;
    }
}

// ---------------------------------------------------------------------------
// Epilogue (unchanged from round 0)
// ---------------------------------------------------------------------------
__global__ __launch_bounds__(256) void bn_stats_kernel(
    const float* __restrict__ X, int nfeat,
    const float* __restrict__ gamma, const float* __restrict__ beta,
    float* __restrict__ s, float* __restrict__ t)
{
    const int f = blockIdx.x * 256 + threadIdx.x;
    if (f >= nfeat) return;
    float sum = 0.f, sq = 0.f;
    for (int b = 0; b < BATCH; ++b) {
        const float v = X[(size_t)b * nfeat + f];
        sum += v; sq += v * v;
    }
    const float mean = sum * (1.f / BATCH);
    const float var  = sq * (1.f / BATCH) - mean * mean;
    const float rstd = rsqrtf(var + 1e-5f);
    const float sc   = gamma[f] * rstd;
    s[f] = sc;
    t[f] = beta[f] - mean * sc;
}

__global__ __launch_bounds__(256) void fc1_kernel(
    const float* __restrict__ h, const float* __restrict__ s1,
    const float* __restrict__ t1, const float* __restrict__ W1,
    const float* __restrict__ b1, float* __restrict__ out1)
{
    const int b = blockIdx.x;
    const int l = threadIdx.x;
    const float* hb = h  + (size_t)b * HDIM;
    const float* wl = W1 + (size_t)l * HDIM;
    float acc = 0.f;
    for (int k = 0; k < HDIM; ++k)
        acc += (hb[k] * s1[k] + t1[k]) * wl[k];
    out1[(size_t)b * LDIM + l] = acc + b1[l];
}

__global__ __launch_bounds__(256) void final_kernel(
    const float* __restrict__ out1, const float* __restrict__ s2,
    const float* __restrict__ t2, const float* __restrict__ W2,
    const float* __restrict__ b2, float* __restrict__ out)
{
    const int b = blockIdx.x;
    float v = out1[(size_t)b * LDIM + threadIdx.x];
    v = v * s2[threadIdx.x] + t2[threadIdx.x];
    v = fmaxf(v, 0.f);
    v *= W2[threadIdx.x];
    #pragma unroll
    for (int off = 32; off > 0; off >>= 1) v += __shfl_down(v, off);
    __shared__ float red[4];
    if ((threadIdx.x & 63) == 0) red[threadIdx.x >> 6] = v;
    __syncthreads();
    if (threadIdx.x == 0) {
        const float ssum = red[0] + red[1] + red[2] + red[3] + b2[0];
        out[b] = 4.f / (1.f + expf(-ssum));
    }
}

// ---------------------------------------------------------------------------
extern "C" void kernel_launch(void* const* d_in, const int* in_sizes, int n_in,
                              void* d_out, int out_size, void* d_ws, size_t ws_size,
                              hipStream_t stream) {
    const float* x   = (const float*)d_in[0];
    const float* Wih = (const float*)d_in[1];
    const float* Whh = (const float*)d_in[2];
    const float* bih = (const float*)d_in[3];
    const float* bhh = (const float*)d_in[4];
    const float* g1  = (const float*)d_in[5];
    const float* be1 = (const float*)d_in[6];
    const float* W1  = (const float*)d_in[7];
    const float* b1  = (const float*)d_in[8];
    const float* g2  = (const float*)d_in[9];
    const float* be2 = (const float*)d_in[10];
    const float* W2  = (const float*)d_in[11];
    const float* b2  = (const float*)d_in[12];
    float* out = (float*)d_out;

    // Workspace layout
    float* ws   = (float*)d_ws;
    float* h    = ws;                         // BATCH*HDIM
    float* c    = h + BATCH * HDIM;           // BATCH*HDIM
    float* bsum = c + BATCH * HDIM;           // G4
    float* s1   = bsum + G4;
    float* t1   = s1 + HDIM;
    float* s2   = t1 + HDIM;
    float* t2   = s2 + LDIM;
    float* out1 = t2 + LDIM;                  // BATCH*LDIM
    _Float16* Wihc = (_Float16*)(out1 + (size_t)BATCH * LDIM);  // G4*KIH
    _Float16* Whhc = Wihc + (size_t)G4 * KIH;                   // G4*HDIM
    // total ≈ 4.3 MB

    hipMemsetAsync(h, 0, (size_t)2 * BATCH * HDIM * sizeof(float), stream);
    prep_kernel<<<G4, 256, 0, stream>>>(Wih, Whh, bih, bhh, Wihc, Whhc, bsum);

    const dim3 sgrid(BATCH / 32, HDIM / 32);
    for (int t = 0; t < SEQ; ++t) {
        fused_step_kernel<<<sgrid, 256, 0, stream>>>(
            x + (size_t)t * BATCH * INDIM, Wihc, Whhc, bsum, c, h);
    }

    bn_stats_kernel<<<2, 256, 0, stream>>>(h, HDIM, g1, be1, s1, t1);
    fc1_kernel<<<BATCH, 256, 0, stream>>>(h, s1, t1, W1, b1, out1);
    bn_stats_kernel<<<1, 256, 0, stream>>>(out1, LDIM, g2, be2, s2, t2);
    final_kernel<<<BATCH, 256, 0, stream>>>(out1, s2, t2, W2, b2, out);
}